// Round 17
// baseline (69.336 us; speedup 1.0000x reference)
//
#include <hip/hip_runtime.h>
#include <hip/hip_bf16.h>

#define B_ 4
#define T_ 4096
#define C_ 1024
#define D_ 128

typedef __attribute__((ext_vector_type(8))) short short8;
typedef __attribute__((ext_vector_type(4))) float f32x4;
typedef __attribute__((ext_vector_type(16))) float f32x16;
typedef __attribute__((ext_vector_type(4))) unsigned short ushort4v;

static __device__ __forceinline__ unsigned short f2b(float f) {
    __hip_bfloat16 h = __float2bfloat16(f);
    return __builtin_bit_cast(unsigned short, h);
}
static __device__ __forceinline__ float b2f(unsigned short u) {
    return __builtin_bit_cast(float, (unsigned int)u << 16);
}

static __device__ __forceinline__ float exp2fast(float x) {
#if __has_builtin(__builtin_amdgcn_exp2f)
    return __builtin_amdgcn_exp2f(x);
#else
    return exp2f(x);
#endif
}

static __device__ __forceinline__ unsigned int pkbf(float lo, float hi) {
    return (unsigned int)f2b(lo) | ((unsigned int)f2b(hi) << 16);
}

// ---------------------------------------------------------------------------
// Kernel 0: W -> bf16 B-FRAGMENT PANELS.
// Wp frag (n16, ks, kf) is a contiguous 1KB wave-load: lane (lg<<4|l16),
// j in 0..7 holds W[n16*16+l16][ks*64+kf*32+lg*8+j].
// ---------------------------------------------------------------------------
__global__ __launch_bounds__(256) void wcvt(
    const float* __restrict__ Wq, const float* __restrict__ Wk,
    const float* __restrict__ Wv, unsigned short* __restrict__ Wp)
{
    int t8 = blockIdx.x * 256 + threadIdx.x;   // 49152 threads, 8 elems each
    int n  = t8 >> 7;                          // 0..383
    int c0 = (t8 & 127) << 3;                  // 0..1016
    const float* src = (n < 128) ? (Wq + (size_t)n * C_ + c0)
                     : (n < 256) ? (Wk + (size_t)(n - 128) * C_ + c0)
                                 : (Wv + (size_t)(n - 256) * C_ + c0);
    float4 a = *(const float4*)src;
    float4 c = *(const float4*)(src + 4);
    short8 o = { (short)f2b(a.x), (short)f2b(a.y), (short)f2b(a.z), (short)f2b(a.w),
                 (short)f2b(c.x), (short)f2b(c.y), (short)f2b(c.z), (short)f2b(c.w) };
    int n16 = n >> 4, l16 = n & 15;
    int ks = c0 >> 6, kf = (c0 >> 5) & 1, lg = (c0 >> 3) & 3;
    int lane = (lg << 4) | l16;
    *(short8*)(Wp + (((size_t)(n16 * 32 + ks * 2 + kf) << 9) + (lane << 3))) = o;
}

// ---------------------------------------------------------------------------
// Kernel A: fused QKV projection. 512 blocks x 512 thr (8 waves, each 32x48).
// Tile 32m x 384n. BK=256 LDS rounds: only THREE barriers in the whole
// kernel (R16 post-mortem: a barrier per k-step + compiler's vmcnt(0) drain
// truncates every prefetch to <1 step of flight -> each of 16 steps paid
// full memory latency). Within a round (4 MFMA k-steps) no barriers: B-panel
// ping-pong streams from L2 (depth-1, ~1 step flight), next-round x loads
// issued at sub 0/2 get ~3 steps of flight, consumed by the round-end LDS
// write. A dbuf 32KB (2 blocks/CU at grid 512). XOR-swizzled (2-way max).
// Epilogue layouts: Q row-major [t][d] (scale*log2e folded);
//   Kp: QK^T A-frag panels  Kp[t/32][d/16][lane][8]
//   Vq: PV   B-frag panels  Vq[t/32][(tl>>4)*4+d/32][lane][8]
// ---------------------------------------------------------------------------
__global__ __launch_bounds__(512, 2) void qkv_gemm(
    const float* __restrict__ x, const unsigned short* __restrict__ Wp,
    unsigned short* __restrict__ qkv)
{
    __shared__ unsigned short Al[2][32][256];
    const int tid = threadIdx.x, lane = tid & 63, w = tid >> 6;
    const int l16 = lane & 15, lg = lane >> 4;
    const int wc = w * 48;              // 8 waves x 48 cols
    const int m0 = blockIdx.x << 5;     // 32-row tile

    const int arow = tid >> 4, ac0 = (tid & 15) << 4;   // 16 floats / thread / round
    const float* aptr = x + (size_t)(m0 + arow) * C_ + ac0;

    float4 xr[4];
    auto writeA = [&](int buf) {
        #pragma unroll
        for (int i = 0; i < 4; i++) {
            int c = ac0 + (i << 2);
            ushort4v h = { f2b(xr[i].x), f2b(xr[i].y), f2b(xr[i].z), f2b(xr[i].w) };
            *(ushort4v*)(&Al[buf][arow][((((c >> 3) ^ (arow & 7)) << 3) | (c & 7))]) = h;
        }
    };

    const unsigned short* wpw = Wp + ((size_t)(w * 3) << 14) + (lane << 3);
    short8 bfA[3][2], bfB[3][2];
    auto loadB = [&](short8 (&bf)[3][2], int gs) {
        #pragma unroll
        for (int nf = 0; nf < 3; nf++)
            #pragma unroll
            for (int kf = 0; kf < 2; kf++)
                bf[nf][kf] = *(const short8*)(wpw + ((size_t)nf << 14) + ((gs * 2 + kf) << 9));
    };

    f32x4 acc[2][3] = {};

    // prologue: x(round 0) -> LDS buf0; B(step 0) -> bfA
    #pragma unroll
    for (int i = 0; i < 4; i++) xr[i] = *(const float4*)(aptr + (i << 2));
    writeA(0);
    loadB(bfA, 0);
    __syncthreads();

    #pragma unroll
    for (int r = 0; r < 4; r++) {
        const int cur = r & 1;
        #pragma unroll
        for (int sub = 0; sub < 4; sub++) {
            const int gs = (r << 2) + sub;
            // next-round x loads: issued early, consumed at round-end writeA
            if (r < 3) {
                if (sub == 0) {
                    xr[0] = *(const float4*)(aptr + (r + 1) * 256);
                    xr[1] = *(const float4*)(aptr + (r + 1) * 256 + 4);
                } else if (sub == 2) {
                    xr[2] = *(const float4*)(aptr + (r + 1) * 256 + 8);
                    xr[3] = *(const float4*)(aptr + (r + 1) * 256 + 12);
                }
            }
            // B ping-pong prefetch for step gs+1 (no barrier in between -> streams)
            if (gs + 1 < 16) { if (gs & 1) loadB(bfA, gs + 1); else loadB(bfB, gs + 1); }
            // A-frags from LDS (swizzled chunks)
            short8 af[2][2];
            #pragma unroll
            for (int mf = 0; mf < 2; mf++) {
                int row = (mf << 4) + l16;
                #pragma unroll
                for (int kf = 0; kf < 2; kf++) {
                    int chunk = ((sub << 3) + (kf << 2) + lg) ^ (row & 7);
                    af[mf][kf] = *(const short8*)(&Al[cur][row][chunk << 3]);
                }
            }
            short8 (&bfC)[3][2] = (gs & 1) ? bfB : bfA;
            #pragma unroll
            for (int kf = 0; kf < 2; kf++)
                #pragma unroll
                for (int mf = 0; mf < 2; mf++)
                    #pragma unroll
                    for (int nf = 0; nf < 3; nf++)
                        acc[mf][nf] = __builtin_amdgcn_mfma_f32_16x16x32_bf16(af[mf][kf], bfC[nf][kf], acc[mf][nf], 0, 0, 0);
        }
        if (r < 3) {
            writeA(cur ^ 1);    // xr loads have had ~3 steps in flight
            __syncthreads();
        }
    }

    const float SQ = 0.08838834764831845f * 1.4426950408889634f;  // 1/sqrt(128)*log2e
    unsigned short* Qo = qkv;
    unsigned short* Kp = qkv + (size_t)B_ * T_ * D_;
    unsigned short* Vq = qkv + 2 * (size_t)B_ * T_ * D_;
    #pragma unroll
    for (int mf = 0; mf < 2; mf++) {
        #pragma unroll
        for (int nf = 0; nf < 3; nf++) {
            int cg  = wc + (nf << 4);
            int mat = cg >> 7;
            int cc  = (cg & 127) + l16;
            #pragma unroll
            for (int r = 0; r < 4; r++) {
                int row = m0 + (mf << 4) + (lg << 2) + r;
                float v = acc[mf][nf][r];
                int t = row & (T_ - 1), bb = row >> 12;
                size_t bo = (size_t)bb << 19;
                if (mat == 0) {
                    Qo[(size_t)row * D_ + cc] = f2b(v * SQ);
                } else if (mat == 1) {
                    Kp[bo + ((size_t)(t >> 5) << 12) + ((size_t)(cc >> 4) << 9)
                       + (((cc >> 3) & 1) << 8) + ((t & 31) << 3) + (cc & 7)] = f2b(v);
                } else {
                    int tl = t & 31;
                    Vq[bo + ((size_t)(t >> 5) << 12)
                       + ((size_t)(((tl >> 4) << 2) + (cc >> 5)) << 9)
                       + ((((tl >> 3) & 1) << 8) + ((cc & 31) << 3)) + (tl & 7)] = f2b(v);
                }
            }
        }
    }
}

// ---------------------------------------------------------------------------
// Kernel B: causal flash attention. 512 blocks x 512 thr. (unchanged)
// One 32-row q-tile per block; blocks beta and beta+256 take complementary
// tiles {p, 127-p}. bf16 RAW-partial merge scratch: LDS 66KB -> 2 blocks/CU;
// natural VGPR ~128 -> 4 waves/SIMD. K-loop: 8-way interleaved key split,
// zero barriers, dense 1KB panel loads, in-register softmax (tree + shfl),
// defer-max, in-reg P->A-frag pack (cndmask+shfl). Reader-side merge.
// ---------------------------------------------------------------------------
__global__ __launch_bounds__(512, 2) void attn_fwd(
    const unsigned short* __restrict__ Q,
    const unsigned short* __restrict__ Kp,
    const unsigned short* __restrict__ Vq,
    float* __restrict__ out)
{
    __shared__ unsigned short scb[8][32][128];   // bf16 RAW partials (64KB)
    __shared__ float mlS[8][32][2];

    const int beta0 = blockIdx.x;
    const int sel   = beta0 >> 8;          // 0: tile p, 1: tile 127-p
    const int beta  = beta0 & 255;
    const int xcd   = beta & 7;
    const int b     = xcd >> 1;
    const int pp    = ((beta >> 3) << 1) | (xcd & 1);   // 0..63
    const int it    = sel ? (127 - pp) : pp;
    const int qb    = it << 5;

    const int tid = threadIdx.x, lane = tid & 63, w = tid >> 6;
    const int l32 = lane & 31, lh = lane >> 5;
    const bool lo = (lh == 0);
    const size_t base = (size_t)b * T_ * D_;
    const unsigned short* Kpb = Kp + ((size_t)b << 19);
    const unsigned short* Vqb = Vq + ((size_t)b << 19);

    // Q B-fragments (scale+log2e folded): qf[ds] = Q[qb+l32][16ds+8lh+j]
    short8 qf[8];
    {
        const unsigned short* qp = Q + base + (size_t)(qb + l32) * D_ + (lh << 3);
        #pragma unroll
        for (int ds = 0; ds < 8; ds++) qf[ds] = *(const short8*)(qp + (ds << 4));
    }
    f32x16 accO[4] = {};
    float m_s = -1e30f, l_s = 0.f;

    short8 ka[8], vb[8];

    auto loadKA = [&](int cc) {
        const unsigned short* kp = Kpb + ((size_t)cc << 12) + (lane << 3);
        #pragma unroll
        for (int i = 0; i < 8; i++) ka[i] = *(const short8*)(kp + (i << 9));
    };
    auto loadVB = [&](int cc) {
        const unsigned short* vp = Vqb + ((size_t)cc << 12) + (lane << 3);
        #pragma unroll
        for (int i = 0; i < 8; i++) vb[i] = *(const short8*)(vp + (i << 9));
    };
    auto qkt = [&]() -> f32x16 {
        f32x16 s = {};
        #pragma unroll
        for (int ds = 0; ds < 8; ds++)
            s = __builtin_amdgcn_mfma_f32_32x32x16_bf16(ka[ds], qf[ds], s, 0, 0, 0);
        return s;
    };
    // softmax + pack + PV for chunk cc whose scores are in s2
    auto process = [&](f32x16 &s2, int cc) {
        if (cc == it) {   // diagonal causal mask
            #pragma unroll
            for (int r = 0; r < 16; r++) {
                int kl = (r & 3) + ((r >> 2) << 3) + (lh << 2);
                if (kl > l32) s2[r] = -1e30f;
            }
        }
        // tree max (depth 4) + cross-half shfl
        float t0 = fmaxf(s2[0], s2[1]),   t1 = fmaxf(s2[2], s2[3]);
        float t2 = fmaxf(s2[4], s2[5]),   t3 = fmaxf(s2[6], s2[7]);
        float t4 = fmaxf(s2[8], s2[9]),   t5 = fmaxf(s2[10], s2[11]);
        float t6 = fmaxf(s2[12], s2[13]), t7 = fmaxf(s2[14], s2[15]);
        t0 = fmaxf(t0, t1); t2 = fmaxf(t2, t3); t4 = fmaxf(t4, t5); t6 = fmaxf(t6, t7);
        float mx = fmaxf(fmaxf(t0, t2), fmaxf(t4, t6));
        mx = fmaxf(mx, __shfl_xor(mx, 32));
        // defer-max rescale (rare)
        if (!__all(mx <= m_s + 8.0f)) {
            float mnew = fmaxf(m_s, mx);
            float al = exp2fast(m_s - mnew);
            m_s = mnew; l_s *= al;
            #pragma unroll
            for (int r = 0; r < 16; r++) {
                float av = __shfl(al, (r & 3) + ((r >> 2) << 3) + (lh << 2));
                accO[0][r] *= av; accO[1][r] *= av; accO[2][r] *= av; accO[3][r] *= av;
            }
        }
        #pragma unroll
        for (int r = 0; r < 16; r++) s2[r] = exp2fast(s2[r] - m_s);
        // tree sum + cross-half shfl
        float u0 = s2[0] + s2[1],   u1 = s2[2] + s2[3];
        float u2 = s2[4] + s2[5],   u3 = s2[6] + s2[7];
        float u4 = s2[8] + s2[9],   u5 = s2[10] + s2[11];
        float u6 = s2[12] + s2[13], u7 = s2[14] + s2[15];
        u0 += u1; u2 += u3; u4 += u5; u6 += u7;
        float rs = (u0 + u2) + (u4 + u6);
        rs += __shfl_xor(rs, 32);
        l_s += rs;
        // pack P -> PV A-frags (verified cndmask + shfl transpose)
        unsigned int A0 = pkbf(s2[0],  s2[1]),  B0 = pkbf(s2[2],  s2[3]);
        unsigned int C0 = pkbf(s2[4],  s2[5]),  D0 = pkbf(s2[6],  s2[7]);
        unsigned int A1 = pkbf(s2[8],  s2[9]),  B1 = pkbf(s2[10], s2[11]);
        unsigned int C1 = pkbf(s2[12], s2[13]), D1 = pkbf(s2[14], s2[15]);
        union { unsigned int u[4]; short8 s; } f0, f1;
        {
            unsigned int u0v = lo ? C0 : A0, v0v = lo ? D0 : B0;
            unsigned int su = (unsigned int)__shfl_xor((int)u0v, 32);
            unsigned int sv = (unsigned int)__shfl_xor((int)v0v, 32);
            f0.u[0] = lo ? A0 : su; f0.u[1] = lo ? B0 : sv;
            f0.u[2] = lo ? su : C0; f0.u[3] = lo ? sv : D0;
        }
        {
            unsigned int u1v = lo ? C1 : A1, v1v = lo ? D1 : B1;
            unsigned int su = (unsigned int)__shfl_xor((int)u1v, 32);
            unsigned int sv = (unsigned int)__shfl_xor((int)v1v, 32);
            f1.u[0] = lo ? A1 : su; f1.u[1] = lo ? B1 : sv;
            f1.u[2] = lo ? su : C1; f1.u[3] = lo ? sv : D1;
        }
        // O += P V
        #pragma unroll
        for (int db = 0; db < 4; db++)
            accO[db] = __builtin_amdgcn_mfma_f32_32x32x16_bf16(f0.s, vb[db], accO[db], 0, 0, 0);
        #pragma unroll
        for (int db = 0; db < 4; db++)
            accO[db] = __builtin_amdgcn_mfma_f32_32x32x16_bf16(f1.s, vb[4 + db], accO[db], 0, 0, 0);
    };

    int c = w;
    if (c <= it) {
        loadKA(c);
        loadVB(c);
        #pragma unroll 1
        while (true) {
            f32x16 s2 = qkt();
            bool hn = (c + 8 <= it);
            if (hn) loadKA(c + 8);      // ka free after QK^T
            process(s2, c);
            if (hn) loadVB(c + 8);      // vb free after PV
            c += 8;
            if (!hn) break;
        }
    }

    // ---- 8-way merge: RAW bf16 partials; all per-q weights in the reader ----
    if (lane < 32) { mlS[w][lane][0] = m_s; mlS[w][lane][1] = l_s; }
    #pragma unroll
    for (int r = 0; r < 16; r++) {
        int q = (r & 3) + ((r >> 2) << 3) + (lh << 2);
        #pragma unroll
        for (int db = 0; db < 4; db++)
            scb[w][q][(db << 5) + l32] = f2b(accO[db][r]);
    }
    __syncthreads();
    {
        const int q = tid >> 4, dc = (tid & 15) << 3;
        float fw[8], mst = -1e30f, lst = 0.f;
        #pragma unroll
        for (int w2 = 0; w2 < 8; w2++) mst = fmaxf(mst, mlS[w2][q][0]);
        #pragma unroll
        for (int w2 = 0; w2 < 8; w2++) {
            fw[w2] = exp2fast(mlS[w2][q][0] - mst);
            lst += fw[w2] * mlS[w2][q][1];
        }
        float inv = 1.0f / lst;
        float o[8] = {};
        #pragma unroll
        for (int w2 = 0; w2 < 8; w2++) {
            short8 sv = *(const short8*)(&scb[w2][q][dc]);
            #pragma unroll
            for (int j = 0; j < 8; j++)
                o[j] += fw[w2] * b2f((unsigned short)sv[j]);
        }
        float* op = out + base + (size_t)(qb + q) * D_ + dc;
        f32x4 o0 = { o[0], o[1], o[2], o[3] };
        f32x4 o1 = { o[4], o[5], o[6], o[7] };
        *(f32x4*)op = o0 * inv;
        *(f32x4*)(op + 4) = o1 * inv;
    }
}

extern "C" void kernel_launch(void* const* d_in, const int* in_sizes, int n_in,
                              void* d_out, int out_size, void* d_ws, size_t ws_size,
                              hipStream_t stream) {
    (void)in_sizes; (void)n_in; (void)out_size; (void)ws_size;
    const float* x  = (const float*)d_in[0];
    const float* Wq = (const float*)d_in[1];
    const float* Wk = (const float*)d_in[2];
    const float* Wv = (const float*)d_in[3];

    unsigned short* qkv = (unsigned short*)d_ws;     // Q | Kp | Vq, bf16, 4MB each
    unsigned short* Wp  = (unsigned short*)d_out;    // temp bf16 W panels (overwritten by attn)

    wcvt<<<dim3(192), 256, 0, stream>>>(Wq, Wk, Wv, Wp);
    qkv_gemm<<<dim3(512), 512, 0, stream>>>(x, Wp, qkv);

    const unsigned short* Qw = qkv;
    const unsigned short* Kw = qkv + (size_t)B_ * T_ * D_;
    const unsigned short* Vw = qkv + 2 * (size_t)B_ * T_ * D_;
    attn_fwd<<<dim3(512), 512, 0, stream>>>(Qw, Kw, Vw, (float*)d_out);
}

// Round 18
// 62.692 us; speedup vs baseline: 1.1060x; 1.1060x over previous
//
#include <hip/hip_runtime.h>
#include <hip/hip_bf16.h>

#define B_ 4
#define T_ 4096
#define C_ 1024
#define D_ 128

typedef __attribute__((ext_vector_type(8))) short short8;
typedef __attribute__((ext_vector_type(4))) float f32x4;
typedef __attribute__((ext_vector_type(16))) float f32x16;
typedef __attribute__((ext_vector_type(4))) unsigned short ushort4v;

static __device__ __forceinline__ unsigned short f2b(float f) {
    __hip_bfloat16 h = __float2bfloat16(f);
    return __builtin_bit_cast(unsigned short, h);
}
static __device__ __forceinline__ float b2f(unsigned short u) {
    return __builtin_bit_cast(float, (unsigned int)u << 16);
}

static __device__ __forceinline__ float exp2fast(float x) {
#if __has_builtin(__builtin_amdgcn_exp2f)
    return __builtin_amdgcn_exp2f(x);
#else
    return exp2f(x);
#endif
}

static __device__ __forceinline__ unsigned int pkbf(float lo, float hi) {
    return (unsigned int)f2b(lo) | ((unsigned int)f2b(hi) << 16);
}

// async global -> LDS, 16B per lane; dest = wave-uniform base + lane*16
static __device__ __forceinline__ void gload_lds16(const void* g, void* l) {
    __builtin_amdgcn_global_load_lds(
        (const __attribute__((address_space(1))) unsigned int*)g,
        (__attribute__((address_space(3))) unsigned int*)l, 16, 0, 0);
}

// ---------------------------------------------------------------------------
// Kernel 0: W -> bf16 B-FRAGMENT PANELS.
// Wp frag (n16, ks, kf) is a contiguous 1KB image: lane (lg<<4|l16), j=0..7
// holds W[n16*16+l16][ks*64+kf*32+lg*8+j].
// ---------------------------------------------------------------------------
__global__ __launch_bounds__(256) void wcvt(
    const float* __restrict__ Wq, const float* __restrict__ Wk,
    const float* __restrict__ Wv, unsigned short* __restrict__ Wp)
{
    int t8 = blockIdx.x * 256 + threadIdx.x;   // 49152 threads, 8 elems each
    int n  = t8 >> 7;                          // 0..383
    int c0 = (t8 & 127) << 3;                  // 0..1016
    const float* src = (n < 128) ? (Wq + (size_t)n * C_ + c0)
                     : (n < 256) ? (Wk + (size_t)(n - 128) * C_ + c0)
                                 : (Wv + (size_t)(n - 256) * C_ + c0);
    float4 a = *(const float4*)src;
    float4 c = *(const float4*)(src + 4);
    short8 o = { (short)f2b(a.x), (short)f2b(a.y), (short)f2b(a.z), (short)f2b(a.w),
                 (short)f2b(c.x), (short)f2b(c.y), (short)f2b(c.z), (short)f2b(c.w) };
    int n16 = n >> 4, l16 = n & 15;
    int ks = c0 >> 6, kf = (c0 >> 5) & 1, lg = (c0 >> 3) & 3;
    int lane = (lg << 4) | l16;
    *(short8*)(Wp + (((size_t)(n16 * 32 + ks * 2 + kf) << 9) + (lane << 3))) = o;
}

// ---------------------------------------------------------------------------
// Kernel A: fused QKV projection. 256 blocks x 1024 thr (16 waves = 2m x 8n),
// 1 block/CU. Tile 64m x 384n, BK=64, 16 k-steps.
// R17 post-mortem: VGPR=52 proved the compiler SANK all register prefetches
// (no regs ever allocated) -> serial latency per step; and M-tile 32 made
// B-L2-traffic 384MB. Fixes: (a) B staged via global_load_lds (no dest reg
// -> cannot be sunk; truly async; drains at the one barrier/step after a
// full step of flight); Wp panels are lane-exact 1KB frag images -> linear
// LDS dest; all 16 waves share the block B tile. (b) M-tile 64 halves B
// traffic. A reg-staged (fp32->bf16) with early-issued x loads.
// LDS: B dbuf 96KB + A dbuf 16KB = 112KB.
// Epilogue layouts: Q row-major [t][d] (scale*log2e folded);
//   Kp: QK^T A-frag panels  Kp[t/32][d/16][lane][8]
//   Vq: PV   B-frag panels  Vq[t/32][(tl>>4)*4+d/32][lane][8]
// ---------------------------------------------------------------------------
__global__ __launch_bounds__(1024, 1) void qkv_gemm(
    const float* __restrict__ x, const unsigned short* __restrict__ Wp,
    unsigned short* __restrict__ qkv)
{
    __shared__ unsigned short Al[2][64][64];     // 16 KB
    __shared__ unsigned short Bl[2][48][512];    // 96 KB (frag = 1KB)
    const int tid = threadIdx.x, lane = tid & 63, w = tid >> 6;  // w 0..15
    const int l16 = lane & 15, lg = lane >> 4;
    const int wm = w >> 3, wn = w & 7;
    const int m0 = blockIdx.x << 6;

    const int arow = tid >> 4, ac4 = (tid & 15) << 2;  // 1 float4/thread/step
    const float* aptr = x + (size_t)(m0 + arow) * C_ + ac4;

    auto writeA = [&](int buf, float4 v) {
        ushort4v h = { f2b(v.x), f2b(v.y), f2b(v.z), f2b(v.w) };
        *(ushort4v*)(&Al[buf][arow][((((ac4 >> 3) ^ (arow & 7)) << 3) | (ac4 & 4))]) = h;
    };
    // B async stage: 3 issues; wave w moves frag f = i*16+w (1KB each)
    auto stageB = [&](int buf, int ks) {
        #pragma unroll
        for (int i = 0; i < 3; i++) {
            int f = (i << 4) + w;                    // 0..47
            int n16 = f >> 1, kf = f & 1;
            const unsigned short* src =
                Wp + (((size_t)(n16 * 32 + ks * 2 + kf)) << 9) + (lane << 3);
            gload_lds16(src, &Bl[buf][f][0]);
        }
    };

    f32x4 acc[2][3] = {};

    // prologue: A(0)+B(0) staged; x(1),x(2) in ping-pong regs
    writeA(0, *(const float4*)(aptr));
    stageB(0, 0);
    float4 rA = *(const float4*)(aptr + 64);
    float4 rB = *(const float4*)(aptr + 128);
    __syncthreads();

    #pragma unroll
    for (int ks = 0; ks < 16; ks++) {
        const int cur = ks & 1;
        if (ks < 15) stageB(cur ^ 1, ks + 1);         // async, full-step flight
        float4 nv; const bool doX = (ks + 3 < 16);
        if (doX) nv = *(const float4*)(aptr + (ks + 3) * 64);   // early issue
        // A-frags from LDS
        short8 af[2][2];
        #pragma unroll
        for (int mf = 0; mf < 2; mf++) {
            int row = (wm << 5) + (mf << 4) + l16;
            #pragma unroll
            for (int kf = 0; kf < 2; kf++)
                af[mf][kf] = *(const short8*)(&Al[cur][row][((((kf << 2) + lg) ^ (row & 7)) << 3)]);
        }
        // B-frags from shared LDS tile
        short8 bf[3][2];
        #pragma unroll
        for (int nf = 0; nf < 3; nf++)
            #pragma unroll
            for (int kf = 0; kf < 2; kf++)
                bf[nf][kf] = *(const short8*)(&Bl[cur][((3 * wn + nf) << 1) | kf][lane << 3]);
        #pragma unroll
        for (int kf = 0; kf < 2; kf++)
            #pragma unroll
            for (int mf = 0; mf < 2; mf++)
                #pragma unroll
                for (int nf = 0; nf < 3; nf++)
                    acc[mf][nf] = __builtin_amdgcn_mfma_f32_16x16x32_bf16(af[mf][kf], bf[nf][kf], acc[mf][nf], 0, 0, 0);
        if (ks < 15) writeA(cur ^ 1, ((ks + 1) & 1) ? rA : rB);
        if (doX) { if ((ks + 3) & 1) rA = nv; else rB = nv; }
        __syncthreads();
    }

    const float SQ = 0.08838834764831845f * 1.4426950408889634f;  // 1/sqrt(128)*log2e
    unsigned short* Qo = qkv;
    unsigned short* Kp = qkv + (size_t)B_ * T_ * D_;
    unsigned short* Vq = qkv + 2 * (size_t)B_ * T_ * D_;
    const int wc = wn * 48;
    #pragma unroll
    for (int mf = 0; mf < 2; mf++) {
        #pragma unroll
        for (int nf = 0; nf < 3; nf++) {
            int cg  = wc + (nf << 4);
            int mat = cg >> 7;
            int cc  = (cg & 127) + l16;
            #pragma unroll
            for (int r = 0; r < 4; r++) {
                int row = m0 + (wm << 5) + (mf << 4) + (lg << 2) + r;
                float v = acc[mf][nf][r];
                int t = row & (T_ - 1), bb = row >> 12;
                size_t bo = (size_t)bb << 19;
                if (mat == 0) {
                    Qo[(size_t)row * D_ + cc] = f2b(v * SQ);
                } else if (mat == 1) {
                    Kp[bo + ((size_t)(t >> 5) << 12) + ((size_t)(cc >> 4) << 9)
                       + (((cc >> 3) & 1) << 8) + ((t & 31) << 3) + (cc & 7)] = f2b(v);
                } else {
                    int tl = t & 31;
                    Vq[bo + ((size_t)(t >> 5) << 12)
                       + ((size_t)(((tl >> 4) << 2) + (cc >> 5)) << 9)
                       + ((((tl >> 3) & 1) << 8) + ((cc & 31) << 3)) + (tl & 7)] = f2b(v);
                }
            }
        }
    }
}

// ---------------------------------------------------------------------------
// Kernel B: causal flash attention. 512 blocks x 512 thr. (unchanged)
// One 32-row q-tile per block; blocks beta and beta+256 take complementary
// tiles {p, 127-p}. bf16 RAW-partial merge scratch: LDS 66KB -> 2 blocks/CU;
// natural VGPR ~128 -> 4 waves/SIMD. K-loop: 8-way interleaved key split,
// zero barriers, dense 1KB panel loads, in-register softmax (tree + shfl),
// defer-max, in-reg P->A-frag pack (cndmask+shfl). Reader-side merge.
// ---------------------------------------------------------------------------
__global__ __launch_bounds__(512, 2) void attn_fwd(
    const unsigned short* __restrict__ Q,
    const unsigned short* __restrict__ Kp,
    const unsigned short* __restrict__ Vq,
    float* __restrict__ out)
{
    __shared__ unsigned short scb[8][32][128];   // bf16 RAW partials (64KB)
    __shared__ float mlS[8][32][2];

    const int beta0 = blockIdx.x;
    const int sel   = beta0 >> 8;          // 0: tile p, 1: tile 127-p
    const int beta  = beta0 & 255;
    const int xcd   = beta & 7;
    const int b     = xcd >> 1;
    const int pp    = ((beta >> 3) << 1) | (xcd & 1);   // 0..63
    const int it    = sel ? (127 - pp) : pp;
    const int qb    = it << 5;

    const int tid = threadIdx.x, lane = tid & 63, w = tid >> 6;
    const int l32 = lane & 31, lh = lane >> 5;
    const bool lo = (lh == 0);
    const size_t base = (size_t)b * T_ * D_;
    const unsigned short* Kpb = Kp + ((size_t)b << 19);
    const unsigned short* Vqb = Vq + ((size_t)b << 19);

    // Q B-fragments (scale+log2e folded): qf[ds] = Q[qb+l32][16ds+8lh+j]
    short8 qf[8];
    {
        const unsigned short* qp = Q + base + (size_t)(qb + l32) * D_ + (lh << 3);
        #pragma unroll
        for (int ds = 0; ds < 8; ds++) qf[ds] = *(const short8*)(qp + (ds << 4));
    }
    f32x16 accO[4] = {};
    float m_s = -1e30f, l_s = 0.f;

    short8 ka[8], vb[8];

    auto loadKA = [&](int cc) {
        const unsigned short* kp = Kpb + ((size_t)cc << 12) + (lane << 3);
        #pragma unroll
        for (int i = 0; i < 8; i++) ka[i] = *(const short8*)(kp + (i << 9));
    };
    auto loadVB = [&](int cc) {
        const unsigned short* vp = Vqb + ((size_t)cc << 12) + (lane << 3);
        #pragma unroll
        for (int i = 0; i < 8; i++) vb[i] = *(const short8*)(vp + (i << 9));
    };
    auto qkt = [&]() -> f32x16 {
        f32x16 s = {};
        #pragma unroll
        for (int ds = 0; ds < 8; ds++)
            s = __builtin_amdgcn_mfma_f32_32x32x16_bf16(ka[ds], qf[ds], s, 0, 0, 0);
        return s;
    };
    // softmax + pack + PV for chunk cc whose scores are in s2
    auto process = [&](f32x16 &s2, int cc) {
        if (cc == it) {   // diagonal causal mask
            #pragma unroll
            for (int r = 0; r < 16; r++) {
                int kl = (r & 3) + ((r >> 2) << 3) + (lh << 2);
                if (kl > l32) s2[r] = -1e30f;
            }
        }
        // tree max (depth 4) + cross-half shfl
        float t0 = fmaxf(s2[0], s2[1]),   t1 = fmaxf(s2[2], s2[3]);
        float t2 = fmaxf(s2[4], s2[5]),   t3 = fmaxf(s2[6], s2[7]);
        float t4 = fmaxf(s2[8], s2[9]),   t5 = fmaxf(s2[10], s2[11]);
        float t6 = fmaxf(s2[12], s2[13]), t7 = fmaxf(s2[14], s2[15]);
        t0 = fmaxf(t0, t1); t2 = fmaxf(t2, t3); t4 = fmaxf(t4, t5); t6 = fmaxf(t6, t7);
        float mx = fmaxf(fmaxf(t0, t2), fmaxf(t4, t6));
        mx = fmaxf(mx, __shfl_xor(mx, 32));
        // defer-max rescale (rare)
        if (!__all(mx <= m_s + 8.0f)) {
            float mnew = fmaxf(m_s, mx);
            float al = exp2fast(m_s - mnew);
            m_s = mnew; l_s *= al;
            #pragma unroll
            for (int r = 0; r < 16; r++) {
                float av = __shfl(al, (r & 3) + ((r >> 2) << 3) + (lh << 2));
                accO[0][r] *= av; accO[1][r] *= av; accO[2][r] *= av; accO[3][r] *= av;
            }
        }
        #pragma unroll
        for (int r = 0; r < 16; r++) s2[r] = exp2fast(s2[r] - m_s);
        // tree sum + cross-half shfl
        float u0 = s2[0] + s2[1],   u1 = s2[2] + s2[3];
        float u2 = s2[4] + s2[5],   u3 = s2[6] + s2[7];
        float u4 = s2[8] + s2[9],   u5 = s2[10] + s2[11];
        float u6 = s2[12] + s2[13], u7 = s2[14] + s2[15];
        u0 += u1; u2 += u3; u4 += u5; u6 += u7;
        float rs = (u0 + u2) + (u4 + u6);
        rs += __shfl_xor(rs, 32);
        l_s += rs;
        // pack P -> PV A-frags (verified cndmask + shfl transpose)
        unsigned int A0 = pkbf(s2[0],  s2[1]),  B0 = pkbf(s2[2],  s2[3]);
        unsigned int C0 = pkbf(s2[4],  s2[5]),  D0 = pkbf(s2[6],  s2[7]);
        unsigned int A1 = pkbf(s2[8],  s2[9]),  B1 = pkbf(s2[10], s2[11]);
        unsigned int C1 = pkbf(s2[12], s2[13]), D1 = pkbf(s2[14], s2[15]);
        union { unsigned int u[4]; short8 s; } f0, f1;
        {
            unsigned int u0v = lo ? C0 : A0, v0v = lo ? D0 : B0;
            unsigned int su = (unsigned int)__shfl_xor((int)u0v, 32);
            unsigned int sv = (unsigned int)__shfl_xor((int)v0v, 32);
            f0.u[0] = lo ? A0 : su; f0.u[1] = lo ? B0 : sv;
            f0.u[2] = lo ? su : C0; f0.u[3] = lo ? sv : D0;
        }
        {
            unsigned int u1v = lo ? C1 : A1, v1v = lo ? D1 : B1;
            unsigned int su = (unsigned int)__shfl_xor((int)u1v, 32);
            unsigned int sv = (unsigned int)__shfl_xor((int)v1v, 32);
            f1.u[0] = lo ? A1 : su; f1.u[1] = lo ? B1 : sv;
            f1.u[2] = lo ? su : C1; f1.u[3] = lo ? sv : D1;
        }
        // O += P V
        #pragma unroll
        for (int db = 0; db < 4; db++)
            accO[db] = __builtin_amdgcn_mfma_f32_32x32x16_bf16(f0.s, vb[db], accO[db], 0, 0, 0);
        #pragma unroll
        for (int db = 0; db < 4; db++)
            accO[db] = __builtin_amdgcn_mfma_f32_32x32x16_bf16(f1.s, vb[4 + db], accO[db], 0, 0, 0);
    };

    int c = w;
    if (c <= it) {
        loadKA(c);
        loadVB(c);
        #pragma unroll 1
        while (true) {
            f32x16 s2 = qkt();
            bool hn = (c + 8 <= it);
            if (hn) loadKA(c + 8);      // ka free after QK^T
            process(s2, c);
            if (hn) loadVB(c + 8);      // vb free after PV
            c += 8;
            if (!hn) break;
        }
    }

    // ---- 8-way merge: RAW bf16 partials; all per-q weights in the reader ----
    if (lane < 32) { mlS[w][lane][0] = m_s; mlS[w][lane][1] = l_s; }
    #pragma unroll
    for (int r = 0; r < 16; r++) {
        int q = (r & 3) + ((r >> 2) << 3) + (lh << 2);
        #pragma unroll
        for (int db = 0; db < 4; db++)
            scb[w][q][(db << 5) + l32] = f2b(accO[db][r]);
    }
    __syncthreads();
    {
        const int q = tid >> 4, dc = (tid & 15) << 3;
        float fw[8], mst = -1e30f, lst = 0.f;
        #pragma unroll
        for (int w2 = 0; w2 < 8; w2++) mst = fmaxf(mst, mlS[w2][q][0]);
        #pragma unroll
        for (int w2 = 0; w2 < 8; w2++) {
            fw[w2] = exp2fast(mlS[w2][q][0] - mst);
            lst += fw[w2] * mlS[w2][q][1];
        }
        float inv = 1.0f / lst;
        float o[8] = {};
        #pragma unroll
        for (int w2 = 0; w2 < 8; w2++) {
            short8 sv = *(const short8*)(&scb[w2][q][dc]);
            #pragma unroll
            for (int j = 0; j < 8; j++)
                o[j] += fw[w2] * b2f((unsigned short)sv[j]);
        }
        float* op = out + base + (size_t)(qb + q) * D_ + dc;
        f32x4 o0 = { o[0], o[1], o[2], o[3] };
        f32x4 o1 = { o[4], o[5], o[6], o[7] };
        *(f32x4*)op = o0 * inv;
        *(f32x4*)(op + 4) = o1 * inv;
    }
}

extern "C" void kernel_launch(void* const* d_in, const int* in_sizes, int n_in,
                              void* d_out, int out_size, void* d_ws, size_t ws_size,
                              hipStream_t stream) {
    (void)in_sizes; (void)n_in; (void)out_size; (void)ws_size;
    const float* x  = (const float*)d_in[0];
    const float* Wq = (const float*)d_in[1];
    const float* Wk = (const float*)d_in[2];
    const float* Wv = (const float*)d_in[3];

    unsigned short* qkv = (unsigned short*)d_ws;     // Q | Kp | Vq, bf16, 4MB each
    unsigned short* Wp  = (unsigned short*)d_out;    // temp bf16 W panels (overwritten by attn)

    wcvt<<<dim3(192), 256, 0, stream>>>(Wq, Wk, Wv, Wp);
    qkv_gemm<<<dim3(256), 1024, 0, stream>>>(x, Wp, qkv);

    const unsigned short* Qw = qkv;
    const unsigned short* Kw = qkv + (size_t)B_ * T_ * D_;
    const unsigned short* Vw = qkv + 2 * (size_t)B_ * T_ * D_;
    attn_fwd<<<dim3(512), 512, 0, stream>>>(Qw, Kw, Vw, (float*)d_out);
}